// Round 1
// baseline (265.101 us; speedup 1.0000x reference)
//
#include <hip/hip_runtime.h>
#include <math.h>

#define LL 2048
#define DD 128
#define NS 16                          // 2 sources * 8 batches
#define SLAB (LL * DD)                 // 262144 elements per (src,n)
#define SCALE 0.08838834764831845f     // 1/sqrt(128)
#define NT 16                          // 128-row tiles per slab
#define NPAIR 136                      // NT*(NT+1)/2 upper-triangle pairs

typedef __attribute__((ext_vector_type(8))) short short8v;   // 8 bf16 (4 VGPR)
typedef __attribute__((ext_vector_type(4))) float float4v;   // MFMA C/D

__device__ __forceinline__ unsigned int f2bf(float f) {   // RNE, low 16 bits
    unsigned int u = __float_as_uint(f);
    u += 0x7fffu + ((u >> 16) & 1u);
    return u >> 16;
}
__device__ __forceinline__ void pair_decode(int p, int& ib, int& jb) {
    int i = 0;
    while (p >= NT - i) { p -= NT - i; ++i; }
    ib = i; jb = i + p;
}

// async global->LDS, 16B per lane; LDS dest = wave-uniform base + lane*16
__device__ __forceinline__ void gl_lds16(const void* g, void* l) {
    __builtin_amdgcn_global_load_lds(
        (const __attribute__((address_space(1))) void*)g,
        (__attribute__((address_space(3))) void*)l, 16, 0, 0);
}

// Stage one 128x32 bf16 chunk of tile gB (already offset to kc*32 cols) into
// panel-layout lbuf: slot c in [0,512): q=c>>7, row=c&127;
// LDS[c*16B] = gB[row*DD + q*8 .. +8]. Frag reads of (row, q=quad) then hit
// 16 consecutive 16B slots per 16-lane group -> conflict-free ds_read_b128.
__device__ __forceinline__ void stage_tile(
    const unsigned short* __restrict__ gB, unsigned short* lbuf, int tid)
{
#pragma unroll
    for (int it = 0; it < 2; ++it) {
        const int c  = tid + it * 256;
        const int cb = (tid & ~63) + it * 256;            // wave-uniform base slot
        gl_lds16(gB + (size_t)(c & 127) * DD + (c >> 7) * 8, lbuf + cb * 8);
    }
}

// ---------------------------------------------------------------------------
// Kernel 1: P = x @ W^T + b (fp32), split to P_hi/P_lo bf16 in d_out.
// Block: 64 l-rows x 128 d. Grid: (32 l-tiles, 16 ns) = 512 blocks.
// ---------------------------------------------------------------------------
__global__ __launch_bounds__(256, 4) void proj_kernel(
    const float* __restrict__ xt, const float* __restrict__ xf,
    const float* __restrict__ W,  const float* __restrict__ bias,
    unsigned short* __restrict__ Ph, unsigned short* __restrict__ Pl)
{
    __shared__ float Alds[64 * 36];
    __shared__ float Blds[128 * 36];
    __shared__ float bs[128];
    const int ns = blockIdx.y;
    const int l0 = blockIdx.x * 64;
    const int src = ns >> 3, n = ns & 7;
    const float* x = (src ? xf : xt) + (size_t)n * LL * DD;
    const int tid = threadIdx.x;
    const int ty = tid >> 4, tx = tid & 15;

    if (tid < 128) bs[tid] = bias[tid];
    __syncthreads();

    float acc[4][8];
#pragma unroll
    for (int i = 0; i < 4; ++i)
#pragma unroll
        for (int j = 0; j < 8; ++j) acc[i][j] = bs[tx + 16 * j];

    for (int kc = 0; kc < 4; ++kc) {
        __syncthreads();
#pragma unroll
        for (int t = 0; t < 2; ++t) {            // x: 64 x 32 = 512 float4
            int idx = tid + t * 256;
            int r = idx >> 3, k4 = (idx & 7) << 2;
            *(float4*)&Alds[r * 36 + k4] =
                *(const float4*)&x[(size_t)(l0 + r) * DD + kc * 32 + k4];
        }
#pragma unroll
        for (int t = 0; t < 4; ++t) {            // W: 128 x 32 = 1024 float4
            int idx = tid + t * 256;
            int r = idx >> 3, k4 = (idx & 7) << 2;
            *(float4*)&Blds[r * 36 + k4] =
                *(const float4*)&W[(size_t)r * DD + kc * 32 + k4];
        }
        __syncthreads();
#pragma unroll
        for (int k4 = 0; k4 < 32; k4 += 4) {
            float4 a4[4], b4[8];
#pragma unroll
            for (int i = 0; i < 4; ++i) a4[i] = *(const float4*)&Alds[(ty + 16 * i) * 36 + k4];
#pragma unroll
            for (int j = 0; j < 8; ++j) b4[j] = *(const float4*)&Blds[(tx + 16 * j) * 36 + k4];
#pragma unroll
            for (int i = 0; i < 4; ++i)
#pragma unroll
                for (int j = 0; j < 8; ++j) {
                    acc[i][j] = fmaf(a4[i].x, b4[j].x, acc[i][j]);
                    acc[i][j] = fmaf(a4[i].y, b4[j].y, acc[i][j]);
                    acc[i][j] = fmaf(a4[i].z, b4[j].z, acc[i][j]);
                    acc[i][j] = fmaf(a4[i].w, b4[j].w, acc[i][j]);
                }
        }
    }
#pragma unroll
    for (int i = 0; i < 4; ++i) {
        const size_t rowo = (size_t)ns * SLAB + (size_t)(l0 + ty + 16 * i) * DD;
#pragma unroll
        for (int j = 0; j < 8; ++j) {
            float p = acc[i][j];
            unsigned int hb = f2bf(p);
            float hf = __uint_as_float(hb << 16);
            unsigned int lb = f2bf(p - hf);
            Ph[rowo + tx + 16 * j] = (unsigned short)hb;
            Pl[rowo + tx + 16 * j] = (unsigned short)lb;
        }
    }
}

// ---------------------------------------------------------------------------
// MFMA bf16x3 GEMM core v2 (hi*hi + hi*lo + lo*hi).
// 4 waves in 2x2 grid; each wave owns a 64x64 quadrant of S(ib,jb).
//   - A frags loaded DIRECT from global (no inter-wave reuse -> skip LDS)
//   - B staged via global_load_lds into conflict-free panel layout,
//     double-buffered (2x16KB), one barrier per kc.
// acc frag (16x16x32): out row = quad*4 + reg, out col = l16.
// ---------------------------------------------------------------------------
__device__ __forceinline__ void mfma_core(
    const unsigned short* __restrict__ Ph, const unsigned short* __restrict__ Pl,
    int ns, int ib, int jb, int tid,
    unsigned short* B0h, unsigned short* B1h,
    unsigned short* B0l, unsigned short* B1l,
    float4v (&acc)[4][4])
{
    const int lane = tid & 63;
    const int quad = lane >> 4, l16 = lane & 15;
    const int wave = tid >> 6;
    const int wr = wave >> 1, wc = wave & 1;

    const unsigned short* sAh = Ph + (size_t)ns * SLAB + (size_t)ib * 128 * DD;
    const unsigned short* sAl = Pl + (size_t)ns * SLAB + (size_t)ib * 128 * DD;
    const unsigned short* sBh = Ph + (size_t)ns * SLAB + (size_t)jb * 128 * DD;
    const unsigned short* sBl = Pl + (size_t)ns * SLAB + (size_t)jb * 128 * DD;

#pragma unroll
    for (int i = 0; i < 4; ++i)
#pragma unroll
        for (int j = 0; j < 4; ++j)
#pragma unroll
            for (int r = 0; r < 4; ++r) acc[i][j][r] = 0.f;

    unsigned short* bufh[2] = {B0h, B1h};
    unsigned short* bufl[2] = {B0l, B1l};

    stage_tile(sBh, bufh[0], tid);
    stage_tile(sBl, bufl[0], tid);
    __syncthreads();

    const int arow0 = wr * 64;
#pragma unroll
    for (int kc = 0; kc < 4; ++kc) {
        // A fragments direct from global (issued FIRST so the vmcnt wait for
        // them does not drain the B prefetch issued below)
        short8v ah[4], al[4];
        const int acol = kc * 32 + quad * 8;
#pragma unroll
        for (int rt = 0; rt < 4; ++rt) {
            const size_t ao = (size_t)(arow0 + rt * 16 + l16) * DD + acol;
            ah[rt] = *(const short8v*)&sAh[ao];
            al[rt] = *(const short8v*)&sAl[ao];
        }
        __builtin_amdgcn_sched_barrier(0);   // keep A loads ahead of prefetch
        if (kc < 3) {                        // prefetch next B chunk
            stage_tile(sBh + (kc + 1) * 32, bufh[(kc + 1) & 1], tid);
            stage_tile(sBl + (kc + 1) * 32, bufl[(kc + 1) & 1], tid);
        }
        const unsigned short* bph = bufh[kc & 1];
        const unsigned short* bpl = bufl[kc & 1];
        short8v bh[4], bl[4];
#pragma unroll
        for (int ct = 0; ct < 4; ++ct) {
            const int off = (quad * 128 + wc * 64 + ct * 16 + l16) * 8;
            bh[ct] = *(const short8v*)&bph[off];
            bl[ct] = *(const short8v*)&bpl[off];
        }
#pragma unroll
        for (int rt = 0; rt < 4; ++rt)
#pragma unroll
            for (int ct = 0; ct < 4; ++ct) {
                acc[rt][ct] = __builtin_amdgcn_mfma_f32_16x16x32_bf16(ah[rt], bh[ct], acc[rt][ct], 0, 0, 0);
                acc[rt][ct] = __builtin_amdgcn_mfma_f32_16x16x32_bf16(ah[rt], bl[ct], acc[rt][ct], 0, 0, 0);
                acc[rt][ct] = __builtin_amdgcn_mfma_f32_16x16x32_bf16(al[rt], bh[ct], acc[rt][ct], 0, 0, 0);
            }
        __syncthreads();
    }
}

// ---------------------------------------------------------------------------
// Kernel 2: per tile-pair UNSHIFTED softmax denominators: Zpart row sums of
// exp(s) for rows of BOTH blocks. Zpart: [(ns*16 + othertile)*2048 + row]
// ---------------------------------------------------------------------------
__global__ __launch_bounds__(256, 3) void stats_kernel(
    const unsigned short* __restrict__ Ph, const unsigned short* __restrict__ Pl,
    float* __restrict__ Zpart)
{
    __shared__ unsigned short B0h[4096], B1h[4096], B0l[4096], B1l[4096]; // 32 KB
    __shared__ float Zr[128][2], Zc[128][2];                               // 2 KB
    int ib, jb;  pair_decode(blockIdx.x, ib, jb);
    const int ns = blockIdx.y;
    const int tid = threadIdx.x;
    const int lane = tid & 63, quad = lane >> 4, l16 = lane & 15, wave = tid >> 6;
    const int wr = wave >> 1, wc = wave & 1;

    float4v acc[4][4];
    mfma_core(Ph, Pl, ns, ib, jb, tid, B0h, B1h, B0l, B1l, acc);

    float cs[4] = {0.f, 0.f, 0.f, 0.f};
#pragma unroll
    for (int rt = 0; rt < 4; ++rt)
#pragma unroll
        for (int rg = 0; rg < 4; ++rg) {
            float e[4];
            float s = 0.f;
#pragma unroll
            for (int ct = 0; ct < 4; ++ct) {
                e[ct] = __expf(acc[rt][ct][rg] * SCALE);
                s += e[ct]; cs[ct] += e[ct];
            }
            s += __shfl_xor(s, 1);
            s += __shfl_xor(s, 2);
            s += __shfl_xor(s, 4);
            s += __shfl_xor(s, 8);
            if (l16 == 0) Zr[wr * 64 + rt * 16 + quad * 4 + rg][wc] = s;
        }

    // transpose partials: sums over this wave's 64 rows for its 64 cols
#pragma unroll
    for (int ct = 0; ct < 4; ++ct) {
        float s = cs[ct];
        s += __shfl_xor(s, 16);
        s += __shfl_xor(s, 32);
        if (quad == 0) Zc[wc * 64 + ct * 16 + l16][wr] = s;
    }
    __syncthreads();
    if (tid < 128) {
        Zpart[(ns * 16 + jb) * LL + ib * 128 + tid] = Zr[tid][0] + Zr[tid][1];
        if (ib != jb)
            Zpart[(ns * 16 + ib) * LL + jb * 128 + tid] = Zc[tid][0] + Zc[tid][1];
    }
}

// ---------------------------------------------------------------------------
// Kernel 3: iZ[row] = 1 / sum of 16 per-tile partials
// ---------------------------------------------------------------------------
__global__ __launch_bounds__(256) void reduce_stats_kernel(
    const float* __restrict__ Zpart, float* __restrict__ iZfin)
{
    const int idx = blockIdx.x * 256 + threadIdx.x;   // ns*2048 + l
    const int ns = idx >> 11, l = idx & 2047;
    float Z = 0.f;
#pragma unroll
    for (int t = 0; t < 16; ++t) Z += Zpart[(ns * 16 + t) * LL + l];
    iZfin[idx] = 1.0f / Z;
}

// ---------------------------------------------------------------------------
// Kernel 4: recompute s (identical MFMA sequence), per-tile column partial
// sums of exp(s)*iZ_row for cols of BOTH blocks. Spart: [(ns*2048+m)*16+tile]
// ---------------------------------------------------------------------------
__global__ __launch_bounds__(256, 3) void colsum_kernel(
    const unsigned short* __restrict__ Ph, const unsigned short* __restrict__ Pl,
    const float* __restrict__ iZfin, float* __restrict__ Spart)
{
    __shared__ unsigned short B0h[4096], B1h[4096], B0l[4096], B1l[4096]; // 32 KB
    __shared__ float Sr[128][2], Sc[128][2];                               // 2 KB
    int ib, jb;  pair_decode(blockIdx.x, ib, jb);
    const int ns = blockIdx.y;
    const int tid = threadIdx.x;
    const int lane = tid & 63, quad = lane >> 4, l16 = lane & 15, wave = tid >> 6;
    const int wr = wave >> 1, wc = wave & 1;

    float4v acc[4][4];
    mfma_core(Ph, Pl, ns, ib, jb, tid, B0h, B1h, B0l, B1l, acc);

    float wrow[4][4];
#pragma unroll
    for (int rt = 0; rt < 4; ++rt)
#pragma unroll
        for (int rg = 0; rg < 4; ++rg)
            wrow[rt][rg] = iZfin[ns * LL + ib * 128 + wr * 64 + rt * 16 + quad * 4 + rg];
    float wcol[4];
#pragma unroll
    for (int ct = 0; ct < 4; ++ct)
        wcol[ct] = iZfin[ns * LL + jb * 128 + wc * 64 + ct * 16 + l16];

    float dsum[4] = {0.f, 0.f, 0.f, 0.f};
#pragma unroll
    for (int rt = 0; rt < 4; ++rt)
#pragma unroll
        for (int rg = 0; rg < 4; ++rg) {
            const int rl = wr * 64 + rt * 16 + quad * 4 + rg;
            float ts = 0.f;
#pragma unroll
            for (int ct = 0; ct < 4; ++ct) {
                float e = __expf(acc[rt][ct][rg] * SCALE);
                bool diag = (ib == jb) && (rl == wc * 64 + ct * 16 + l16);
                dsum[ct] += diag ? 0.f : e * wrow[rt][rg];
                ts += e * wcol[ct];
            }
            if (ib != jb) {
                ts += __shfl_xor(ts, 1);
                ts += __shfl_xor(ts, 2);
                ts += __shfl_xor(ts, 4);
                ts += __shfl_xor(ts, 8);
                if (l16 == 0) Sr[rl][wc] = ts;
            }
        }

#pragma unroll
    for (int ct = 0; ct < 4; ++ct) {
        float s = dsum[ct];
        s += __shfl_xor(s, 16);
        s += __shfl_xor(s, 32);
        if (quad == 0) Sc[wc * 64 + ct * 16 + l16][wr] = s;
    }
    __syncthreads();
    if (tid < 128) {
        Spart[((size_t)ns * LL + jb * 128 + tid) * 16 + ib] = Sc[tid][0] + Sc[tid][1];
        if (ib != jb)
            Spart[((size_t)ns * LL + ib * 128 + tid) * 16 + jb] = Sr[tid][0] + Sr[tid][1];
    }
}

// ---------------------------------------------------------------------------
// Kernel 5: score = fp64 sum of 16 tile partials; exact bottom-k mask via
// rank counting: mask[i] = #{j: score_j < score_i} < 1024
// ---------------------------------------------------------------------------
__global__ __launch_bounds__(1024) void mask_kernel(
    const float* __restrict__ Spart, unsigned char* __restrict__ maskbuf)
{
    __shared__ double s[LL];
    const int ns = blockIdx.x;
    const int half = blockIdx.y;
    const int tid = threadIdx.x;
#pragma unroll
    for (int h = 0; h < 2; ++h) {
        int m = tid + h * 1024;
        const float* sp = Spart + ((size_t)ns * LL + m) * 16;
        double a = 0.0;
#pragma unroll
        for (int t = 0; t < 16; ++t) a += (double)sp[t];
        s[m] = a;
    }
    __syncthreads();
    const int i = half * 1024 + tid;
    const double si = s[i];
    int cnt = 0;
    for (int j = 0; j < LL; ++j) cnt += (s[j] < si) ? 1 : 0;
    maskbuf[ns * LL + i] = (cnt < 1024) ? 1 : 0;
}

// ---------------------------------------------------------------------------
// Kernel 6: blend, all fp32.
// ---------------------------------------------------------------------------
__global__ __launch_bounds__(256) void blend_kernel(
    const float* __restrict__ xt, const float* __restrict__ xf,
    const unsigned char* __restrict__ maskbuf, float* __restrict__ out)
{
    const int idx4 = blockIdx.x * 256 + threadIdx.x;
    const size_t q = (size_t)idx4 * 4;
    const int row = (int)(q >> 7);
    const float4 a = *(const float4*)(xt + q);
    const float4 b = *(const float4*)(xf + q);
    const int mt = maskbuf[row] & 1;
    const int mf = maskbuf[16384 + row] & 1;
    const bool ct = mt && !mf;
    const bool cf = mf && !mt;
    float4 av;
    av.x = 0.5f * (a.x + b.x);  av.y = 0.5f * (a.y + b.y);
    av.z = 0.5f * (a.z + b.z);  av.w = 0.5f * (a.w + b.w);
    float4 o0 = ct ? av : a;
    float4 o1 = cf ? av : b;
    *(float4*)(out + q)                   = o0;
    *(float4*)(out + (size_t)2097152 + q) = o1;
}

// ---------------------------------------------------------------------------
extern "C" void kernel_launch(void* const* d_in, const int* in_sizes, int n_in,
                              void* d_out, int out_size, void* d_ws, size_t ws_size,
                              hipStream_t stream)
{
    const float* xt = (const float*)d_in[0];
    const float* xf = (const float*)d_in[1];
    const float* W  = (const float*)d_in[2];
    const float* b  = (const float*)d_in[3];
    float* out = (float*)d_out;

    // d_out (16.8 MB) holds P split: Ph bf16 [0,8.39MB), Pl bf16 [8.39,16.8MB).
    // Both dead before blend overwrites d_out.
    unsigned short* Ph = (unsigned short*)d_out;
    unsigned short* Pl = Ph + (size_t)NS * SLAB;

    float* Zpart = (float*)d_ws;                       // 16*16*2048 = 524288 f
    float* iZfin = Zpart + 16 * 16 * LL;               // 32768 f
    float* Spart = iZfin + NS * LL;                    // 524288 f
    unsigned char* maskbuf = (unsigned char*)(Spart + (size_t)16 * LL * 16);
    // total ws ~4.4 MB

    proj_kernel<<<dim3(32, NS), 256, 0, stream>>>(xt, xf, W, b, Ph, Pl);
    stats_kernel<<<dim3(NPAIR, NS), 256, 0, stream>>>(Ph, Pl, Zpart);
    reduce_stats_kernel<<<128, 256, 0, stream>>>(Zpart, iZfin);
    colsum_kernel<<<dim3(NPAIR, NS), 256, 0, stream>>>(Ph, Pl, iZfin, Spart);
    mask_kernel<<<dim3(NS, 2), 1024, 0, stream>>>(Spart, maskbuf);
    blend_kernel<<<2048, 256, 0, stream>>>(xt, xf, maskbuf, out);
}